// Round 2
// baseline (352.182 us; speedup 1.0000x reference)
//
#include <hip/hip_runtime.h>
#include <hip/hip_bf16.h>

typedef __attribute__((ext_vector_type(8))) short short8;
typedef __attribute__((ext_vector_type(4))) float floatx4;

#define NN 4096

static __device__ __forceinline__ unsigned f2bf_rne(float x) {
    union { float f; unsigned u; } v; v.f = x;
    unsigned r = v.u + 0x7fffu + ((v.u >> 16) & 1u);
    return r >> 16;
}

// ---- kernel0: Wc = W1@W2 (64x64 row-major), w1a[0:64]=W1@aL, w1a[64:128]=W1@aR
__global__ void wc_kernel(const float* __restrict__ W1,
                          const float* __restrict__ W2,
                          const float* __restrict__ alpha,
                          float* __restrict__ Wc,
                          float* __restrict__ w1a) {
    __shared__ float red[4][64];
    const int k = blockIdx.x;
    const int t = threadIdx.x;
    const int c = t & 63, mq = t >> 6;
    float p = 0.f;
    #pragma unroll
    for (int mm = 0; mm < 16; ++mm) {
        int m = mq * 16 + mm;
        p += W1[k * 64 + m] * W2[m * 64 + c];
    }
    red[mq][c] = p;
    __syncthreads();
    if (t < 64) {
        Wc[k * 64 + t] = (red[0][t] + red[1][t]) + (red[2][t] + red[3][t]);
        float v = W1[k * 64 + t];
        float pl = v * alpha[t], pr = v * alpha[64 + t];
        #pragma unroll
        for (int off = 32; off > 0; off >>= 1) {
            pl += __shfl_xor(pl, off, 64);
            pr += __shfl_xor(pr, off, 64);
        }
        if (t == 0) { w1a[k] = pl; w1a[64 + k] = pr; }
    }
}

// ---- prep: G = X@Wc -> store G^T bf16 [b*64+c][4096]; lv = X@w1aL; rv = X@w1aR
__global__ void prep_kernel(const float* __restrict__ X,
                            const float* __restrict__ Wc,
                            const float* __restrict__ w1a,
                            unsigned short* __restrict__ Gt,
                            float* __restrict__ lv,
                            float* __restrict__ rv) {
    __shared__ float Xs[64][68];   // stride 68 words: 16B-aligned rows, broadcast reads
    __shared__ float w1s[128];
    const int t = threadIdx.x;
    const int row0 = blockIdx.x * 64;            // flat b*N + n
    const int b = row0 >> 12, n0 = row0 & (NN - 1);
    const int c = t & 63, rq = t >> 6;

    #pragma unroll
    for (int s = 0; s < 4; ++s) {
        int fidx = s * 1024 + t * 4;
        int row = fidx >> 6, k4 = fidx & 63;
        *(float4*)&Xs[row][k4] = *(const float4*)(X + (size_t)row0 * 64 + fidx);
    }
    if (t < 128) w1s[t] = w1a[t];
    float w[64];                                  // Wc column c in VGPRs
    #pragma unroll
    for (int k = 0; k < 64; ++k) w[k] = Wc[k * 64 + c];
    __syncthreads();

    float h[16];
    #pragma unroll
    for (int rr = 0; rr < 16; ++rr) {
        const int rl = rr * 4 + rq;
        float a0 = 0, a1 = 0, a2 = 0, a3 = 0;
        #pragma unroll
        for (int k4 = 0; k4 < 16; ++k4) {
            float4 xv = *(const float4*)&Xs[rl][k4 * 4];
            a0 += xv.x * w[k4 * 4 + 0];
            a1 += xv.y * w[k4 * 4 + 1];
            a2 += xv.z * w[k4 * 4 + 2];
            a3 += xv.w * w[k4 * 4 + 3];
        }
        h[rr] = (a0 + a1) + (a2 + a3);
    }
    // lv/rv: thread = (row = t>>2, kq = t&3)
    {
        int row = t >> 2, kq = t & 3;
        float sl = 0, sr = 0;
        #pragma unroll
        for (int kk = 0; kk < 16; ++kk) {
            int k = kq * 16 + kk;
            float x = Xs[row][k];
            sl += x * w1s[k];
            sr += x * w1s[64 + k];
        }
        sl += __shfl_xor(sl, 1, 64); sl += __shfl_xor(sl, 2, 64);
        sr += __shfl_xor(sr, 1, 64); sr += __shfl_xor(sr, 2, 64);
        if (kq == 0) { lv[row0 + row] = sl; rv[row0 + row] = sr; }
    }
    __syncthreads();
    #pragma unroll
    for (int rr = 0; rr < 16; ++rr) Xs[c][rr * 4 + rq] = h[rr];
    __syncthreads();
    unsigned* Gu = (unsigned*)Gt;
    #pragma unroll
    for (int it2 = 0; it2 < 8; ++it2) {
        int c2 = (t >> 5) + it2 * 8;
        int np = t & 31;
        unsigned lo = f2bf_rne(Xs[c2][2 * np]);
        unsigned hi = f2bf_rne(Xs[c2][2 * np + 1]);
        Gu[(((((size_t)(b * 64 + c2)) << 12) + n0) >> 1) + np] = lo | (hi << 16);
    }
}

// ---- attn: num[b,i,c] = sum_j e_ij*G[j,c]; den[b,i] = sum_j e_ij
// 1024 threads = 16 waves; wave = (isub = w>>2, b = w&3); i-tile 64, j-chunk 1024
__global__ __launch_bounds__(1024)
void attn_kernel(const float* __restrict__ A,
                 const unsigned short* __restrict__ Gt,
                 const float* __restrict__ lv,
                 const float* __restrict__ rv,
                 float* __restrict__ num,
                 float* __restrict__ den) {
    __shared__ float rs[4 * 1024];          // rv per batch for this j-chunk
    __shared__ float2 As2[64 * 17];         // A-tile 64 x 32, row stride 34 floats
    const int bx = blockIdx.x;
    const int i0 = (bx & 63) * 64;
    const int jbase = (bx >> 6) * 1024;
    const int t = threadIdx.x;
    const int wave = t >> 6, lane = t & 63;
    const int b = wave & 3, isub = wave >> 2;
    const int m = lane & 15, q = lane >> 4;
    const int il = isub * 16 + m;
    const int i = i0 + il;

    #pragma unroll
    for (int s = 0; s < 4; ++s)
        rs[s * 1024 + t] = rv[s * NN + jbase + t];

    const float li = lv[b * NN + i] * 1.44269504f;     // fold log2e (leaky commutes)
    const unsigned short* gb = Gt + (((size_t)(b * 64 + m)) << 12) + jbase;

    const int srow = t >> 4, scol = t & 15;
    const float* agp = A + (size_t)(i0 + srow) * NN + jbase + scol * 2;

    floatx4 acc0 = {0,0,0,0}, acc1 = {0,0,0,0}, acc2 = {0,0,0,0}, acc3 = {0,0,0,0};
    float denp = 0.f;

    float2 pv = *(const float2*)agp;
    for (int jj0 = 0; jj0 < 1024; jj0 += 32) {
        __syncthreads();
        As2[srow * 17 + scol] = pv;
        if (jj0 + 32 < 1024) pv = *(const float2*)(agp + jj0 + 32);
        __syncthreads();

        const float2* ap = &As2[il * 17 + q * 4];
        float2 av01 = ap[0], av23 = ap[1], av45 = ap[2], av67 = ap[3];
        const float av[8] = {av01.x, av01.y, av23.x, av23.y,
                             av45.x, av45.y, av67.x, av67.y};
        const float* rp = &rs[b * 1024 + jj0 + q * 8];
        const int jq = jbase + jj0 + q * 8;
        unsigned up[8];
        #pragma unroll
        for (int e = 0; e < 8; ++e) {
            float aa = (jq + e == i) ? 1.0f : av[e];
            float s2 = li * rp[e];
            s2 = fmaxf(s2, 0.01f * s2);                 // leaky_relu slope 0.01
            float ev = exp2f(s2) * aa;
            denp += ev;
            up[e] = __float_as_uint(ev) + 0x8000u;      // round-half-up bf16
        }
        union { uint4 u; short8 s; } pk;
        pk.u.x = __builtin_amdgcn_perm(up[1], up[0], 0x07060302u);
        pk.u.y = __builtin_amdgcn_perm(up[3], up[2], 0x07060302u);
        pk.u.z = __builtin_amdgcn_perm(up[5], up[4], 0x07060302u);
        pk.u.w = __builtin_amdgcn_perm(up[7], up[6], 0x07060302u);
        short8 afr = pk.s;

        const unsigned short* hb = gb + jj0 + q * 8;
        short8 b0 = *(const short8*)(hb);
        short8 b1 = *(const short8*)(hb + (16u << 12));
        short8 b2 = *(const short8*)(hb + (32u << 12));
        short8 b3 = *(const short8*)(hb + (48u << 12));
        acc0 = __builtin_amdgcn_mfma_f32_16x16x32_bf16(afr, b0, acc0, 0, 0, 0);
        acc1 = __builtin_amdgcn_mfma_f32_16x16x32_bf16(afr, b1, acc1, 0, 0, 0);
        acc2 = __builtin_amdgcn_mfma_f32_16x16x32_bf16(afr, b2, acc2, 0, 0, 0);
        acc3 = __builtin_amdgcn_mfma_f32_16x16x32_bf16(afr, b3, acc3, 0, 0, 0);
    }

    denp += __shfl_xor(denp, 16, 64);
    denp += __shfl_xor(denp, 32, 64);
    if (lane < 16) atomicAdd(&den[b * NN + i0 + isub * 16 + lane], denp);

    // C/D layout: col = lane&15, row = (lane>>4)*4 + reg
    #pragma unroll
    for (int nt = 0; nt < 4; ++nt) {
        floatx4 acc = nt == 0 ? acc0 : nt == 1 ? acc1 : nt == 2 ? acc2 : acc3;
        #pragma unroll
        for (int rg = 0; rg < 4; ++rg) {
            int ii = i0 + isub * 16 + q * 4 + rg;
            int ccol = nt * 16 + m;
            atomicAdd(&num[((size_t)(b * NN + ii) << 6) + ccol], acc[rg]);
        }
    }
}

// ---- out: out = num / den
__global__ void out_kernel(const float* __restrict__ num,
                           const float* __restrict__ den,
                           float* __restrict__ out) {
    int i4 = blockIdx.x * 256 + threadIdx.x;
    float4 v = ((const float4*)num)[i4];
    float r = 1.0f / den[i4 >> 4];
    float4 o; o.x = v.x * r; o.y = v.y * r; o.z = v.z * r; o.w = v.w * r;
    ((float4*)out)[i4] = o;
}

extern "C" void kernel_launch(void* const* d_in, const int* in_sizes, int n_in,
                              void* d_out, int out_size, void* d_ws, size_t ws_size,
                              hipStream_t stream) {
    const float* X     = (const float*)d_in[0];
    const float* A     = (const float*)d_in[1];
    const float* W1    = (const float*)d_in[2];
    const float* W2    = (const float*)d_in[3];
    const float* alpha = (const float*)d_in[4];
    float* out = (float*)d_out;

    char* ws = (char*)d_ws;
    unsigned short* Gt = (unsigned short*)(ws);            // 2 MiB
    float* lvp = (float*)(ws + 2097152);                   // 64 KiB
    float* rvp = (float*)(ws + 2097152 + 65536);           // 64 KiB
    float* num = (float*)(ws + 2228224);                   // 4 MiB
    float* den = (float*)(ws + 6422528);                   // 64 KiB
    float* Wc  = (float*)(ws + 6488064);                   // 16 KiB
    float* w1a = (float*)(ws + 6504448);                   // 512 B

    hipMemsetAsync(num, 0, 4194304 + 65536, stream);       // num + den
    wc_kernel<<<64, 256, 0, stream>>>(W1, W2, alpha, Wc, w1a);
    prep_kernel<<<256, 256, 0, stream>>>(X, Wc, w1a, Gt, lvp, rvp);
    attn_kernel<<<256, 1024, 0, stream>>>(A, Gt, lvp, rvp, num, den);
    out_kernel<<<1024, 256, 0, stream>>>(num, den, out);
}

// Round 3
// 324.251 us; speedup vs baseline: 1.0861x; 1.0861x over previous
//
#include <hip/hip_runtime.h>
#include <hip/hip_bf16.h>

typedef __attribute__((ext_vector_type(8))) short short8;
typedef __attribute__((ext_vector_type(4))) float floatx4;

#define NN 4096

static __device__ __forceinline__ unsigned f2bf_rne(float x) {
    union { float f; unsigned u; } v; v.f = x;
    unsigned r = v.u + 0x7fffu + ((v.u >> 16) & 1u);
    return r >> 16;
}

// ---- kernel0: Wc = W1@W2 (64x64 row-major), w1a[0:64]=W1@aL, w1a[64:128]=W1@aR
__global__ void wc_kernel(const float* __restrict__ W1,
                          const float* __restrict__ W2,
                          const float* __restrict__ alpha,
                          float* __restrict__ Wc,
                          float* __restrict__ w1a) {
    __shared__ float red[4][64];
    const int k = blockIdx.x;
    const int t = threadIdx.x;
    const int c = t & 63, mq = t >> 6;
    float p = 0.f;
    #pragma unroll
    for (int mm = 0; mm < 16; ++mm) {
        int m = mq * 16 + mm;
        p += W1[k * 64 + m] * W2[m * 64 + c];
    }
    red[mq][c] = p;
    __syncthreads();
    if (t < 64) {
        Wc[k * 64 + t] = (red[0][t] + red[1][t]) + (red[2][t] + red[3][t]);
        float v = W1[k * 64 + t];
        float pl = v * alpha[t], pr = v * alpha[64 + t];
        #pragma unroll
        for (int off = 32; off > 0; off >>= 1) {
            pl += __shfl_xor(pl, off, 64);
            pr += __shfl_xor(pr, off, 64);
        }
        if (t == 0) { w1a[k] = pl; w1a[64 + k] = pr; }
    }
}

// ---- prep: G = X@Wc -> store G^T bf16 [b*64+c][4096]; lv = X@w1aL; rv = X@w1aR
// __launch_bounds__(256,2): cap at 2 waves/EU so w[64] stays in VGPRs (R2: the
// default 8-wave target forced VGPR=64 and spilled w[] -> 254 MB scratch writes).
__global__ __launch_bounds__(256, 2)
void prep_kernel(const float* __restrict__ X,
                 const float* __restrict__ Wc,
                 const float* __restrict__ w1a,
                 unsigned short* __restrict__ Gt,
                 float* __restrict__ lv,
                 float* __restrict__ rv) {
    __shared__ float Xs[64][68];
    __shared__ float w1s[128];
    const int t = threadIdx.x;
    const int row0 = blockIdx.x * 64;            // flat b*N + n
    const int b = row0 >> 12, n0 = row0 & (NN - 1);
    const int c = t & 63, rq = t >> 6;

    #pragma unroll
    for (int s = 0; s < 4; ++s) {
        int fidx = s * 1024 + t * 4;
        int row = fidx >> 6, k4 = fidx & 63;
        *(float4*)&Xs[row][k4] = *(const float4*)(X + (size_t)row0 * 64 + fidx);
    }
    if (t < 128) w1s[t] = w1a[t];
    float w[64];                                  // Wc column c in VGPRs
    #pragma unroll
    for (int k = 0; k < 64; ++k) w[k] = Wc[k * 64 + c];
    __syncthreads();

    float h[16];
    #pragma unroll
    for (int rr = 0; rr < 16; ++rr) {
        const int rl = rr * 4 + rq;              // wave-uniform row -> LDS broadcast
        float a0 = 0, a1 = 0, a2 = 0, a3 = 0;
        #pragma unroll
        for (int k4 = 0; k4 < 16; ++k4) {
            float4 xv = *(const float4*)&Xs[rl][k4 * 4];
            a0 += xv.x * w[k4 * 4 + 0];
            a1 += xv.y * w[k4 * 4 + 1];
            a2 += xv.z * w[k4 * 4 + 2];
            a3 += xv.w * w[k4 * 4 + 3];
        }
        h[rr] = (a0 + a1) + (a2 + a3);
    }
    {   // lv/rv: thread = (row = t>>2, kq = t&3)
        int row = t >> 2, kq = t & 3;
        float sl = 0, sr = 0;
        #pragma unroll
        for (int kk = 0; kk < 16; ++kk) {
            int k = kq * 16 + kk;
            float x = Xs[row][k];
            sl += x * w1s[k];
            sr += x * w1s[64 + k];
        }
        sl += __shfl_xor(sl, 1, 64); sl += __shfl_xor(sl, 2, 64);
        sr += __shfl_xor(sr, 1, 64); sr += __shfl_xor(sr, 2, 64);
        if (kq == 0) { lv[row0 + row] = sl; rv[row0 + row] = sr; }
    }
    __syncthreads();
    #pragma unroll
    for (int rr = 0; rr < 16; ++rr) Xs[c][rr * 4 + rq] = h[rr];
    __syncthreads();
    unsigned* Gu = (unsigned*)Gt;
    #pragma unroll
    for (int it2 = 0; it2 < 8; ++it2) {
        int c2 = (t >> 5) + it2 * 8;
        int np = t & 31;
        unsigned lo = f2bf_rne(Xs[c2][2 * np]);
        unsigned hi = f2bf_rne(Xs[c2][2 * np + 1]);
        Gu[(((((size_t)(b * 64 + c2)) << 12) + n0) >> 1) + np] = lo | (hi << 16);
    }
}

// ---- attn: num[b,i,c] = sum_j e_ij*G[j,c]; den[b,i] = sum_j e_ij
// R1 structure (256 thr, wave w -> i rows w*16+m) + j-split 8 (2048 blocks)
// + software prefetch of next iteration's A/Gt loads.
__global__ __launch_bounds__(256, 4)
void attn_kernel(const float* __restrict__ A,
                 const unsigned short* __restrict__ Gt,
                 const float* __restrict__ lv,
                 const float* __restrict__ rv,
                 float* __restrict__ num,
                 float* __restrict__ den) {
    __shared__ __align__(16) float rs[512];
    const int bx = blockIdx.x;
    const int i0 = (bx & 63) * 64;
    const int b  = (bx >> 6) & 3;
    const int jbase = (bx >> 8) * 512;
    const int t = threadIdx.x;
    const int w = t >> 6, lane = t & 63;
    const int m = lane & 15, q = lane >> 4;
    const int i = i0 + w * 16 + m;

    rs[t]       = rv[b * NN + jbase + t];
    rs[t + 256] = rv[b * NN + jbase + t + 256];
    __syncthreads();

    const float li = lv[b * NN + i] * 1.44269504f;   // fold log2e (leaky commutes)
    const float* adjRow = A + (size_t)i * NN + jbase;
    const unsigned short* gb = Gt + (((size_t)(b * 64 + m)) << 12) + jbase;
    const int jq0 = q * 8;

    floatx4 acc0 = {0,0,0,0}, acc1 = {0,0,0,0}, acc2 = {0,0,0,0}, acc3 = {0,0,0,0};
    float denp = 0.f;

    float4 pa0 = *(const float4*)(adjRow + jq0);
    float4 pa1 = *(const float4*)(adjRow + jq0 + 4);
    short8 pb0 = *(const short8*)(gb + jq0);
    short8 pb1 = *(const short8*)(gb + jq0 + (16 << 12));
    short8 pb2 = *(const short8*)(gb + jq0 + (32 << 12));
    short8 pb3 = *(const short8*)(gb + jq0 + (48 << 12));

    for (int jj0 = 0; jj0 < 512; jj0 += 32) {
        float4 a0 = pa0, a1 = pa1;
        short8 b0 = pb0, b1 = pb1, b2 = pb2, b3 = pb3;
        const int jn = (jj0 + 32) & 511;             // wraps to 0 on last iter (harmless)
        pa0 = *(const float4*)(adjRow + jn + jq0);
        pa1 = *(const float4*)(adjRow + jn + jq0 + 4);
        pb0 = *(const short8*)(gb + jn + jq0);
        pb1 = *(const short8*)(gb + jn + jq0 + (16 << 12));
        pb2 = *(const short8*)(gb + jn + jq0 + (32 << 12));
        pb3 = *(const short8*)(gb + jn + jq0 + (48 << 12));

        float4 r0 = *(const float4*)(&rs[jj0 + jq0]);
        float4 r1 = *(const float4*)(&rs[jj0 + jq0 + 4]);
        const float av[8]  = {a0.x, a0.y, a0.z, a0.w, a1.x, a1.y, a1.z, a1.w};
        const float rvv[8] = {r0.x, r0.y, r0.z, r0.w, r1.x, r1.y, r1.z, r1.w};
        const int jq = jbase + jj0 + jq0;
        unsigned up[8];
        #pragma unroll
        for (int e = 0; e < 8; ++e) {
            float aa = (jq + e == i) ? 1.0f : av[e]; // diag forced to 1.0
            float s2 = li * rvv[e];
            s2 = fmaxf(s2, 0.01f * s2);              // leaky_relu slope 0.01
            float ev = exp2f(s2) * aa;
            denp += ev;
            up[e] = __float_as_uint(ev) + 0x8000u;   // round-half-up bf16
        }
        union { uint4 u; short8 s; } pk;
        pk.u.x = __builtin_amdgcn_perm(up[1], up[0], 0x07060302u);
        pk.u.y = __builtin_amdgcn_perm(up[3], up[2], 0x07060302u);
        pk.u.z = __builtin_amdgcn_perm(up[5], up[4], 0x07060302u);
        pk.u.w = __builtin_amdgcn_perm(up[7], up[6], 0x07060302u);
        short8 afr = pk.s;

        acc0 = __builtin_amdgcn_mfma_f32_16x16x32_bf16(afr, b0, acc0, 0, 0, 0);
        acc1 = __builtin_amdgcn_mfma_f32_16x16x32_bf16(afr, b1, acc1, 0, 0, 0);
        acc2 = __builtin_amdgcn_mfma_f32_16x16x32_bf16(afr, b2, acc2, 0, 0, 0);
        acc3 = __builtin_amdgcn_mfma_f32_16x16x32_bf16(afr, b3, acc3, 0, 0, 0);
    }

    denp += __shfl_xor(denp, 16, 64);
    denp += __shfl_xor(denp, 32, 64);
    if (lane < 16) atomicAdd(&den[b * NN + i0 + w * 16 + lane], denp);

    // C/D layout: col = lane&15, row = (lane>>4)*4 + reg  (m89-verified)
    #pragma unroll
    for (int nt = 0; nt < 4; ++nt) {
        floatx4 acc = nt == 0 ? acc0 : nt == 1 ? acc1 : nt == 2 ? acc2 : acc3;
        #pragma unroll
        for (int rg = 0; rg < 4; ++rg) {
            int ii = i0 + w * 16 + q * 4 + rg;
            int ccol = nt * 16 + m;
            atomicAdd(&num[((size_t)(b * NN + ii) << 6) + ccol], acc[rg]);
        }
    }
}

// ---- out: out = num / den
__global__ void out_kernel(const float* __restrict__ num,
                           const float* __restrict__ den,
                           float* __restrict__ out) {
    int i4 = blockIdx.x * 256 + threadIdx.x;
    float4 v = ((const float4*)num)[i4];
    float r = 1.0f / den[i4 >> 4];
    float4 o; o.x = v.x * r; o.y = v.y * r; o.z = v.z * r; o.w = v.w * r;
    ((float4*)out)[i4] = o;
}

extern "C" void kernel_launch(void* const* d_in, const int* in_sizes, int n_in,
                              void* d_out, int out_size, void* d_ws, size_t ws_size,
                              hipStream_t stream) {
    const float* X     = (const float*)d_in[0];
    const float* A     = (const float*)d_in[1];
    const float* W1    = (const float*)d_in[2];
    const float* W2    = (const float*)d_in[3];
    const float* alpha = (const float*)d_in[4];
    float* out = (float*)d_out;

    char* ws = (char*)d_ws;
    unsigned short* Gt = (unsigned short*)(ws);            // 2 MiB
    float* lvp = (float*)(ws + 2097152);                   // 64 KiB
    float* rvp = (float*)(ws + 2097152 + 65536);           // 64 KiB
    float* num = (float*)(ws + 2228224);                   // 4 MiB
    float* den = (float*)(ws + 6422528);                   // 64 KiB
    float* Wc  = (float*)(ws + 6488064);                   // 16 KiB
    float* w1a = (float*)(ws + 6504448);                   // 512 B

    hipMemsetAsync(num, 0, 4194304 + 65536, stream);       // num + den
    wc_kernel<<<64, 256, 0, stream>>>(W1, W2, alpha, Wc, w1a);
    prep_kernel<<<256, 256, 0, stream>>>(X, Wc, w1a, Gt, lvp, rvp);
    attn_kernel<<<2048, 256, 0, stream>>>(A, Gt, lvp, rvp, num, den);
    out_kernel<<<1024, 256, 0, stream>>>(num, den, out);
}

// Round 4
// 150.677 us; speedup vs baseline: 2.3373x; 2.1520x over previous
//
#include <hip/hip_runtime.h>
#include <hip/hip_bf16.h>

typedef __attribute__((ext_vector_type(8))) short short8;
typedef __attribute__((ext_vector_type(4))) float floatx4;

#define NN 4096

static __device__ __forceinline__ unsigned f2bf_rne(float x) {
    union { float f; unsigned u; } v; v.f = x;
    unsigned r = v.u + 0x7fffu + ((v.u >> 16) & 1u);
    return r >> 16;
}
static __device__ __forceinline__ float bf2f(unsigned hi) {
    union { unsigned u; float f; } v; v.u = hi << 16; return v.f;
}

// ---- wc: Wfb[n*64+k] = bf16(W1@W2)[k][n] (B-frag-friendly: k contiguous per n);
//          w1a[0:64]=W1@aL, w1a[64:128]=W1@aR (fp32)
__global__ void wc_kernel(const float* __restrict__ W1,
                          const float* __restrict__ W2,
                          const float* __restrict__ alpha,
                          unsigned short* __restrict__ Wfb,
                          float* __restrict__ w1a) {
    __shared__ float red[4][64];
    const int k = blockIdx.x;
    const int t = threadIdx.x;
    const int c = t & 63, mq = t >> 6;
    float p = 0.f;
    #pragma unroll
    for (int mm = 0; mm < 16; ++mm) {
        int mrow = mq * 16 + mm;
        p += W1[k * 64 + mrow] * W2[mrow * 64 + c];
    }
    red[mq][c] = p;
    __syncthreads();
    if (t < 64) {
        float wcv = (red[0][t] + red[1][t]) + (red[2][t] + red[3][t]);
        Wfb[t * 64 + k] = (unsigned short)f2bf_rne(wcv);   // [n=t][k]
        float v = W1[k * 64 + t];
        float pl = v * alpha[t], pr = v * alpha[64 + t];
        #pragma unroll
        for (int off = 32; off > 0; off >>= 1) {
            pl += __shfl_xor(pl, off, 64);
            pr += __shfl_xor(pr, off, 64);
        }
        if (t == 0) { w1a[k] = pl; w1a[64 + k] = pr; }
    }
}

// ---- prep (all-MFMA): G = X@Wc -> Gt bf16 [b*64+c][4096]; lv/rv fp32 exact path.
// X split into bf16 hi+lo so only Wc's bf16 rounding remains in G.
__global__ __launch_bounds__(256, 4)
void prep_kernel(const float* __restrict__ X,
                 const unsigned short* __restrict__ Wfb,
                 const float* __restrict__ w1a,
                 unsigned short* __restrict__ Gt,
                 float* __restrict__ lv,
                 float* __restrict__ rv) {
    __shared__ float w1s[128];
    __shared__ float Gs[64][68];
    const int t = threadIdx.x;
    const int row0 = blockIdx.x * 64;            // flat b*N + n
    const int b = row0 >> 12, n0 = row0 & (NN - 1);
    const int w = t >> 6, lane = t & 63;
    const int m = lane & 15, q = lane >> 4;
    if (t < 128) w1s[t] = w1a[t];

    const int row = row0 + w * 16 + m;
    const float* xp = X + (size_t)row * 64;
    float4 x0 = *(const float4*)(xp + q * 8);
    float4 x1 = *(const float4*)(xp + q * 8 + 4);
    float4 x2 = *(const float4*)(xp + 32 + q * 8);
    float4 x3 = *(const float4*)(xp + 32 + q * 8 + 4);
    const float xs[16] = {x0.x,x0.y,x0.z,x0.w, x1.x,x1.y,x1.z,x1.w,
                          x2.x,x2.y,x2.z,x2.w, x3.x,x3.y,x3.z,x3.w};
    __syncthreads();

    // lv/rv in fp32: lane holds k = ks*32 + q*8 + j
    float pl = 0.f, pr = 0.f;
    #pragma unroll
    for (int ks = 0; ks < 2; ++ks)
        #pragma unroll
        for (int j = 0; j < 8; ++j) {
            int k = ks * 32 + q * 8 + j;
            float xv = xs[ks * 8 + j];
            pl += xv * w1s[k];
            pr += xv * w1s[64 + k];
        }
    pl += __shfl_xor(pl, 16, 64); pl += __shfl_xor(pl, 32, 64);
    pr += __shfl_xor(pr, 16, 64); pr += __shfl_xor(pr, 32, 64);
    if (q == 0) { lv[row] = pl; rv[row] = pr; }

    // bf16 hi/lo A-fragments
    short8 ah[2], al[2];
    #pragma unroll
    for (int ks = 0; ks < 2; ++ks)
        #pragma unroll
        for (int j = 0; j < 8; ++j) {
            float f = xs[ks * 8 + j];
            unsigned hb = f2bf_rne(f);
            float res = f - bf2f(hb);
            ah[ks][j] = (short)hb;
            al[ks][j] = (short)f2bf_rne(res);
        }

    floatx4 acc[4] = {{0,0,0,0},{0,0,0,0},{0,0,0,0},{0,0,0,0}};
    #pragma unroll
    for (int ks = 0; ks < 2; ++ks)
        #pragma unroll
        for (int nt = 0; nt < 4; ++nt) {
            short8 bf = *(const short8*)(Wfb + (nt * 16 + m) * 64 + ks * 32 + q * 8);
            acc[nt] = __builtin_amdgcn_mfma_f32_16x16x32_bf16(ah[ks], bf, acc[nt], 0, 0, 0);
            acc[nt] = __builtin_amdgcn_mfma_f32_16x16x32_bf16(al[ks], bf, acc[nt], 0, 0, 0);
        }

    // epilogue: C/D (col=lane&15, row=q*4+reg) -> LDS transpose -> packed Gt store
    #pragma unroll
    for (int nt = 0; nt < 4; ++nt)
        #pragma unroll
        for (int rg = 0; rg < 4; ++rg)
            Gs[nt * 16 + m][w * 16 + q * 4 + rg] = acc[nt][rg];
    __syncthreads();
    unsigned* Gu = (unsigned*)Gt;
    #pragma unroll
    for (int it2 = 0; it2 < 8; ++it2) {
        int c2 = (t >> 5) + it2 * 8;
        int np = t & 31;
        unsigned lo = f2bf_rne(Gs[c2][2 * np]);
        unsigned hi = f2bf_rne(Gs[c2][2 * np + 1]);
        Gu[(((((size_t)(b * 64 + c2)) << 12) + n0) >> 1) + np] = lo | (hi << 16);
    }
}

// ---- attn: producer-computes-E. Block = (b, 64-i tile, 1024-j split); 256 thr.
// Thread (irow=t>>2, jseg=t&3) loads A coalesced, makes E in regs, writes bf16
// E straight into LDS in A-frag layout; Gt staged once per iter (no 4x redundant
// scattered reads). Registered prefetch across the barrier.
__global__ __launch_bounds__(256, 4)
void attn_kernel(const float* __restrict__ A,
                 const unsigned short* __restrict__ Gt,
                 const float* __restrict__ lv,
                 const float* __restrict__ rv,
                 float* __restrict__ num,
                 float* __restrict__ den) {
    __shared__ float rs[1024];
    __shared__ float lis[64];
    __shared__ __align__(16) unsigned short Es[64 * 40];  // stride 40: 2-way only
    __shared__ __align__(16) unsigned short Gs[64 * 40];
    const int bx = blockIdx.x;
    const int i0 = (bx & 63) * 64;
    const int b  = (bx >> 6) & 3;
    const int jbase = (bx >> 8) * 1024;
    const int t = threadIdx.x;
    const int w = t >> 6, lane = t & 63;
    const int m = lane & 15, q = lane >> 4;
    const int irow = t >> 2;                 // 0..63: i-row (E) / c-row (Gt) staged
    const int jseg = t & 3;                  // 8-j segment

    *(float4*)&rs[t * 4] = *(const float4*)(rv + b * NN + jbase + t * 4);
    if (t < 64) lis[t] = lv[b * NN + i0 + t] * 1.44269504f;  // fold log2e

    const float* aRow = A + (size_t)(i0 + irow) * NN + jbase + jseg * 8;
    const unsigned short* gRow = Gt + (((size_t)(b * 64 + irow)) << 12) + jbase + jseg * 8;
    const int ii = i0 + irow;

    __syncthreads();
    const float li = lis[irow];

    floatx4 acc0 = {0,0,0,0}, acc1 = {0,0,0,0}, acc2 = {0,0,0,0}, acc3 = {0,0,0,0};
    float denp = 0.f;

    float4 pa0 = *(const float4*)(aRow);
    float4 pa1 = *(const float4*)(aRow + 4);
    uint4  pg  = *(const uint4*)(gRow);

    for (int jj = 0; jj < 1024; jj += 32) {
        float4 a0 = pa0, a1 = pa1;
        uint4 g = pg;
        const int jn = (jj + 32 < 1024) ? jj + 32 : jj;   // clamp: no OOB on last iter
        pa0 = *(const float4*)(aRow + jn);
        pa1 = *(const float4*)(aRow + jn + 4);
        pg  = *(const uint4*)(gRow + jn);

        const float av[8] = {a0.x, a0.y, a0.z, a0.w, a1.x, a1.y, a1.z, a1.w};
        const float* rp = &rs[jj + jseg * 8];
        const int jglob = jbase + jj + jseg * 8;
        unsigned up[8];
        #pragma unroll
        for (int e = 0; e < 8; ++e) {
            float aa = (jglob + e == ii) ? 1.0f : av[e];   // diag forced to 1
            float s2 = li * rp[e];
            s2 = fmaxf(s2, 0.01f * s2);                    // leaky_relu slope .01
            float ev = exp2f(s2) * aa;
            denp += ev;
            up[e] = __float_as_uint(ev) + 0x8000u;         // round-half-up bf16
        }
        uint4 epk;
        epk.x = __builtin_amdgcn_perm(up[1], up[0], 0x07060302u);
        epk.y = __builtin_amdgcn_perm(up[3], up[2], 0x07060302u);
        epk.z = __builtin_amdgcn_perm(up[5], up[4], 0x07060302u);
        epk.w = __builtin_amdgcn_perm(up[7], up[6], 0x07060302u);

        __syncthreads();                                   // prev MFMA reads done
        *(uint4*)&Es[irow * 40 + jseg * 8] = epk;
        *(uint4*)&Gs[irow * 40 + jseg * 8] = g;
        __syncthreads();                                   // tiles ready

        short8 afr = *(const short8*)&Es[(w * 16 + m) * 40 + q * 8];
        short8 b0  = *(const short8*)&Gs[(m)      * 40 + q * 8];
        short8 b1  = *(const short8*)&Gs[(16 + m) * 40 + q * 8];
        short8 b2  = *(const short8*)&Gs[(32 + m) * 40 + q * 8];
        short8 b3  = *(const short8*)&Gs[(48 + m) * 40 + q * 8];
        acc0 = __builtin_amdgcn_mfma_f32_16x16x32_bf16(afr, b0, acc0, 0, 0, 0);
        acc1 = __builtin_amdgcn_mfma_f32_16x16x32_bf16(afr, b1, acc1, 0, 0, 0);
        acc2 = __builtin_amdgcn_mfma_f32_16x16x32_bf16(afr, b2, acc2, 0, 0, 0);
        acc3 = __builtin_amdgcn_mfma_f32_16x16x32_bf16(afr, b3, acc3, 0, 0, 0);
    }

    // den: reduce over jseg lanes (xor 1,2), one atomic per i-row
    denp += __shfl_xor(denp, 1, 64);
    denp += __shfl_xor(denp, 2, 64);
    if ((lane & 3) == 0) atomicAdd(&den[b * NN + ii], denp);

    // C/D layout: col = lane&15, row = q*4 + reg (m89-verified)
    #pragma unroll
    for (int nt = 0; nt < 4; ++nt) {
        floatx4 acc = nt == 0 ? acc0 : nt == 1 ? acc1 : nt == 2 ? acc2 : acc3;
        #pragma unroll
        for (int rg = 0; rg < 4; ++rg) {
            int ir = i0 + w * 16 + q * 4 + rg;
            int cc = nt * 16 + m;
            atomicAdd(&num[((size_t)(b * NN + ir) << 6) + cc], acc[rg]);
        }
    }
}

// ---- out: out = num / den
__global__ void out_kernel(const float* __restrict__ num,
                           const float* __restrict__ den,
                           float* __restrict__ out) {
    int i4 = blockIdx.x * 256 + threadIdx.x;
    float4 v = ((const float4*)num)[i4];
    float r = 1.0f / den[i4 >> 4];
    float4 o; o.x = v.x * r; o.y = v.y * r; o.z = v.z * r; o.w = v.w * r;
    ((float4*)out)[i4] = o;
}

extern "C" void kernel_launch(void* const* d_in, const int* in_sizes, int n_in,
                              void* d_out, int out_size, void* d_ws, size_t ws_size,
                              hipStream_t stream) {
    const float* X     = (const float*)d_in[0];
    const float* A     = (const float*)d_in[1];
    const float* W1    = (const float*)d_in[2];
    const float* W2    = (const float*)d_in[3];
    const float* alpha = (const float*)d_in[4];
    float* out = (float*)d_out;

    char* ws = (char*)d_ws;
    unsigned short* Gt  = (unsigned short*)(ws);           // 2 MiB
    float* lvp = (float*)(ws + 2097152);                   // 64 KiB
    float* rvp = (float*)(ws + 2097152 + 65536);           // 64 KiB
    float* num = (float*)(ws + 2228224);                   // 4 MiB
    float* den = (float*)(ws + 6422528);                   // 64 KiB
    unsigned short* Wfb = (unsigned short*)(ws + 6488064); // 8 KiB
    float* w1a = (float*)(ws + 6496256);                   // 512 B

    hipMemsetAsync(num, 0, 4194304 + 65536, stream);       // num + den
    wc_kernel<<<64, 256, 0, stream>>>(W1, W2, alpha, Wfb, w1a);
    prep_kernel<<<256, 256, 0, stream>>>(X, Wfb, w1a, Gt, lvp, rvp);
    attn_kernel<<<1024, 256, 0, stream>>>(A, Gt, lvp, rvp, num, den);
    out_kernel<<<1024, 256, 0, stream>>>(num, den, out);
}